// Round 11
// baseline (780.432 us; speedup 1.0000x reference)
//
#include <hip/hip_runtime.h>
#include <hip/hip_bf16.h>
#include <math.h>

#define N_NODES 50000
#define N_EDGES 800000
#define HID 128
#define LAT 64
#define IN_NODE 11
#define K_EDGE 261    // 2*HID + 1 + 4
#define KP1 288       // K_EDGE padded to multiple of 32
#define KN 256        // node MLP folded K (h + agg)
#define AST 296       // edge feature LDS row stride (bf16 elems), 288+8 pad
#define NST 264       // node feature LDS row stride, 256+8 pad
#define TST 136       // t1 LDS row stride, 128+8 pad
#define MST 132       // msg LDS row stride (floats), 128+4 pad
#define NTPB 20       // edge tiles per block (grid 1250)
#define NTN 4         // node tiles per block (grid 391)
#define NSCAN 196     // scan blocks: 196*256 = 50176 >= N_NODES
// prep_all block partition
#define EB 3125       // edge count+tail blocks
#define EMB_B 25000   // embedding blocks (2 nodes each)
#define WPB 32        // weight prep blocks
#define ZB 100        // agg zero blocks

typedef __attribute__((ext_vector_type(8))) short short8;
typedef __attribute__((ext_vector_type(4))) short short4v;
typedef __attribute__((ext_vector_type(4))) float floatx4;

__device__ __forceinline__ float elu_f(float v) { return v > 0.0f ? v : __expf(v) - 1.0f; }

__device__ __forceinline__ short f2bf(float f) {
    unsigned int u = __builtin_bit_cast(unsigned int, f);
    u += 0x7fffu + ((u >> 16) & 1u);   // round-to-nearest-even
    return (short)(u >> 16);
}

__device__ __forceinline__ short2 f2bf2(float a, float b) {
    float2 p; p.x = a; p.y = b;
    __hip_bfloat162 h = __float22bfloat162_rn(p);   // v_cvt_pk_bf16_f32
    short2 r;
    __builtin_memcpy(&r, &h, sizeof(r));
    return r;
}

__device__ __forceinline__ float bf2f(short s) {
    unsigned int u = ((unsigned int)(unsigned short)s) << 16;
    return __builtin_bit_cast(float, u);
}

// ---------------- fused prep: edge count+tail | emb | weight prep | agg zero ----------------
__global__ void prep_all(const int* __restrict__ edges, const float* __restrict__ x,
                         const float* __restrict__ edge_attr, const float* __restrict__ h0,
                         const float* __restrict__ emb_w, const float* __restrict__ emb_b,
                         const float* __restrict__ ew1, const float* __restrict__ ew2,
                         const float* __restrict__ nw1, const float* __restrict__ nw2,
                         int* __restrict__ cnt, short* __restrict__ tail_u,
                         short* __restrict__ h_bf,
                         short* __restrict__ ew1T, short* __restrict__ ew2T,
                         short* __restrict__ nw1T, short* __restrict__ nw2T,
                         float* __restrict__ agg) {
    int b = blockIdx.x, t = threadIdx.x;
    if (b < EB) {
        // ---- edge: count + radial + bf16 tail pack ----
        int e = b * 256 + t;
        if (e >= N_EDGES) return;
        int r = edges[e], c = edges[N_EDGES + e];
        atomicAdd(&cnt[r], 1);
        float dx = x[r*3+0] - x[c*3+0];
        float dy = x[r*3+1] - x[c*3+1];
        float dz = x[r*3+2] - x[c*3+2];
        float radial = dx*dx + dy*dy + dz*dz;
        float4 ea = *(const float4*)(edge_attr + (size_t)e * 4);
        short8 s = { f2bf(radial), f2bf(ea.x), f2bf(ea.y), f2bf(ea.z), f2bf(ea.w), 0, 0, 0 };
        *(short8*)(tail_u + (size_t)e * 8) = s;
    } else if (b < EB + EMB_B) {
        // ---- embedding: h_bf = bf16(h0 @ emb_w + emb_b) ----
        int bb = b - EB;
        int n = bb * 2 + (t >> 7);
        int c = t & 127;
        if (n >= N_NODES) return;
        float acc = emb_b[c];
        #pragma unroll
        for (int k = 0; k < IN_NODE; ++k) acc += h0[n*IN_NODE + k] * emb_w[k*HID + c];
        h_bf[(size_t)n*HID + c] = f2bf(acc);
    } else if (b < EB + EMB_B + WPB) {
        // ---- weight prep: transpose + bf16 + pad/fold ----
        int idx = (b - EB - EMB_B) * 256 + t;
        int stride = WPB * 256;
        for (int i = idx; i < 2*128*KP1; i += stride) {
            int l = i / (128*KP1); int r = i % (128*KP1);
            int c = r / KP1; int k = r % KP1;
            float v = (k < K_EDGE) ? ew1[(size_t)l*K_EDGE*128 + (size_t)k*128 + c] : 0.0f;
            ew1T[i] = f2bf(v);
        }
        for (int i = idx; i < 2*128*128; i += stride) {
            int l = i / (128*128); int r = i % (128*128);
            int c = r / 128; int k = r % 128;
            ew2T[i] = f2bf(ew2[(size_t)l*128*128 + (size_t)k*128 + c]);
        }
        for (int i = idx; i < 2*128*KN; i += stride) {
            int l = i / (128*KN); int r = i % (128*KN);
            int c = r / KN; int k = r % KN;
            const float* base = nw1 + (size_t)l*384*128;
            float v = (k < 128) ? (base[(size_t)k*128 + c] + base[(size_t)(256+k)*128 + c])
                                : base[(size_t)k*128 + c];
            nw1T[i] = f2bf(v);
        }
        for (int i = idx; i < 2*128*128; i += stride) {
            int l = i / (128*128); int r = i % (128*128);
            int c = r / 128; int k = r % 128;
            nw2T[i] = f2bf(nw2[(size_t)l*128*128 + (size_t)k*128 + c]);
        }
    } else {
        // ---- agg zero ----
        int idx = (b - EB - EMB_B - WPB) * 256 + t;
        int stride = ZB * 256;
        float4 z = {0,0,0,0};
        float4* a4 = (float4*)agg;
        for (int i = idx; i < N_NODES*HID/4; i += stride) a4[i] = z;
    }
}

// ---------------- CSR pass 2a: per-block exclusive scan (256 rows/block) ----------------
__global__ void scan_a(const int* __restrict__ cnt, int* __restrict__ cursor,
                       int* __restrict__ blk) {
    __shared__ int s[256];
    int b = blockIdx.x, t = threadIdx.x;
    int row = b * 256 + t;
    int v = (row < N_NODES) ? cnt[row] : 0;
    s[t] = v;
    __syncthreads();
    #pragma unroll
    for (int off = 1; off < 256; off <<= 1) {
        int add = (t >= off) ? s[t - off] : 0;
        __syncthreads();
        s[t] += add;
        __syncthreads();
    }
    if (row < N_NODES) cursor[row] = s[t] - v;     // exclusive within block
    if (t == 255) blk[b] = s[255];                 // block total
}

// ---------------- CSR pass 2b: exclusivize the 196 block totals ----------------
__global__ void scan_b(int* __restrict__ blk) {
    __shared__ int s[256];
    int t = threadIdx.x;
    int v = (t < NSCAN) ? blk[t] : 0;
    s[t] = v;
    __syncthreads();
    #pragma unroll
    for (int off = 1; off < 256; off <<= 1) {
        int add = (t >= off) ? s[t - off] : 0;
        __syncthreads();
        s[t] += add;
        __syncthreads();
    }
    if (t < NSCAN) blk[t] = s[t] - v;              // exclusive block offset
}

// ---------------- CSR pass 3: place srow/scol/tail in sorted order ----------------
__global__ void csr_place(const int* __restrict__ edges, const short* __restrict__ tail_u,
                          int* __restrict__ cursor, const int* __restrict__ blk,
                          int* __restrict__ srow, int* __restrict__ scol,
                          short* __restrict__ tail_s) {
    int e = blockIdx.x * 256 + threadIdx.x;
    if (e >= N_EDGES) return;
    int r = edges[e], c = edges[N_EDGES + e];
    short8 s = *(const short8*)(tail_u + (size_t)e * 8);
    int pos = atomicAdd(&cursor[r], 1) + blk[r >> 8];
    srow[pos] = r; scol[pos] = c;
    *(short8*)(tail_s + (size_t)pos * 8) = s;
}

// ---------------- MFMA edge MLP: register weights, prefetch-pipelined tiles ----------------
__global__ __launch_bounds__(256, 2) void edge_mfma_kernel(
    const short* __restrict__ h_bf, const short* __restrict__ tail_s,
    const int* __restrict__ srow, const int* __restrict__ scol,
    const short* __restrict__ w1T, const float* __restrict__ b1,
    const short* __restrict__ w2T, const float* __restrict__ b2,
    float* __restrict__ agg)
{
    __shared__ __align__(16) short featA[32 * AST];   // 18944 B; msg overlays here
    __shared__ __align__(16) short t1[32 * TST];      // 8704 B
    __shared__ int srowS[32];
    float* msgF = (float*)featA;                      // 32 x MST floats = 16896 B <= featA
    int t = threadIdx.x;
    int lane = t & 63;
    int wv = t >> 6;          // wave: channel block [wv*32, wv*32+32)
    int l15 = lane & 15;
    int quad = lane >> 4;
    int el = t >> 3, j = t & 7;

    // ---- preload this wave's weight fragments into registers (once) ----
    short8 aw1[2][9], aw2[2][4];
    float4 b1v[2], b2v[2];
    #pragma unroll
    for (int mi = 0; mi < 2; ++mi) {
        #pragma unroll
        for (int ks = 0; ks < 9; ++ks)
            aw1[mi][ks] = *(const short8*)&w1T[(size_t)(wv*32 + mi*16 + l15)*KP1 + ks*32 + quad*8];
        #pragma unroll
        for (int ks = 0; ks < 4; ++ks)
            aw2[mi][ks] = *(const short8*)&w2T[(size_t)(wv*32 + mi*16 + l15)*128 + ks*32 + quad*8];
        b1v[mi] = *(const float4*)&b1[wv*32 + mi*16 + quad*4];
        b2v[mi] = *(const float4*)&b2[wv*32 + mi*16 + quad*4];
    }

    int ebase = blockIdx.x * NTPB * 32;

    // ---- prefetch tile 0 into registers ----
    int r = srow[ebase + el];
    int c = scol[ebase + el];
    short8 p0, p1, p2, p3, ptail;
    {
        const short8* hr = (const short8*)(h_bf + (size_t)r * HID + j*16);
        const short8* hc = (const short8*)(h_bf + (size_t)c * HID + j*16);
        p0 = hr[0]; p1 = hr[1]; p2 = hc[0]; p3 = hc[1];
        if (t < 32) ptail = *(const short8*)(tail_s + (size_t)(ebase + t) * 8);
    }

    for (int it = 0; it < NTPB; ++it) {
        __syncthreads();   // prior iteration's msg reads done before featA overwrite

        // ---- commit prefetched tile to LDS ----
        if (j == 0) srowS[el] = r;
        *(short8*)&featA[el*AST + j*16]           = p0;
        *(short8*)&featA[el*AST + j*16 + 8]       = p1;
        *(short8*)&featA[el*AST + 128 + j*16]     = p2;
        *(short8*)&featA[el*AST + 128 + j*16 + 8] = p3;
        if (t < 32) {
            short8 z = {0,0,0,0,0,0,0,0};
            *(short8*)&featA[t*AST + 256] = ptail;
            *(short8*)&featA[t*AST + 264] = z;
            *(short8*)&featA[t*AST + 272] = z;
            *(short8*)&featA[t*AST + 280] = z;
        }
        __syncthreads();

        // ---- prefetch next tile (latency hidden under MFMA below) ----
        if (it + 1 < NTPB) {
            int e2 = ebase + (it + 1) * 32;
            r = srow[e2 + el];
            c = scol[e2 + el];
            const short8* hr = (const short8*)(h_bf + (size_t)r * HID + j*16);
            const short8* hc = (const short8*)(h_bf + (size_t)c * HID + j*16);
            p0 = hr[0]; p1 = hr[1]; p2 = hc[0]; p3 = hc[1];
            if (t < 32) ptail = *(const short8*)(tail_s + (size_t)(e2 + t) * 8);
        }

        // ---- layer 1: K = 288, A resident ----
        floatx4 acc[2][2] = {{{0,0,0,0},{0,0,0,0}},{{0,0,0,0},{0,0,0,0}}};
        #pragma unroll
        for (int ks = 0; ks < 9; ++ks) {
            int koff = ks*32 + quad*8;
            short8 bb0 = *(const short8*)&featA[l15*AST + koff];
            short8 bb1 = *(const short8*)&featA[(16 + l15)*AST + koff];
            acc[0][0] = __builtin_amdgcn_mfma_f32_16x16x32_bf16(aw1[0][ks], bb0, acc[0][0], 0, 0, 0);
            acc[0][1] = __builtin_amdgcn_mfma_f32_16x16x32_bf16(aw1[0][ks], bb1, acc[0][1], 0, 0, 0);
            acc[1][0] = __builtin_amdgcn_mfma_f32_16x16x32_bf16(aw1[1][ks], bb0, acc[1][0], 0, 0, 0);
            acc[1][1] = __builtin_amdgcn_mfma_f32_16x16x32_bf16(aw1[1][ks], bb1, acc[1][1], 0, 0, 0);
        }

        // ---- epilogue 1: bias + elu -> bf16 t1[e][c] (packed cvt) ----
        #pragma unroll
        for (int mi = 0; mi < 2; ++mi) {
            int cb = wv*32 + mi*16 + quad*4;
            #pragma unroll
            for (int ni = 0; ni < 2; ++ni) {
                short2 q0 = f2bf2(elu_f(acc[mi][ni][0] + b1v[mi].x),
                                  elu_f(acc[mi][ni][1] + b1v[mi].y));
                short2 q1 = f2bf2(elu_f(acc[mi][ni][2] + b1v[mi].z),
                                  elu_f(acc[mi][ni][3] + b1v[mi].w));
                short4v s = { q0.x, q0.y, q1.x, q1.y };
                *(short4v*)&t1[(ni*16 + l15)*TST + cb] = s;
            }
        }
        __syncthreads();   // featA reads done (L1 K-loop) -> msg overlay safe after here

        // ---- layer 2: K = 128, A resident ----
        floatx4 acc2[2][2] = {{{0,0,0,0},{0,0,0,0}},{{0,0,0,0},{0,0,0,0}}};
        #pragma unroll
        for (int ks = 0; ks < 4; ++ks) {
            int koff = ks*32 + quad*8;
            short8 bb0 = *(const short8*)&t1[l15*TST + koff];
            short8 bb1 = *(const short8*)&t1[(16 + l15)*TST + koff];
            acc2[0][0] = __builtin_amdgcn_mfma_f32_16x16x32_bf16(aw2[0][ks], bb0, acc2[0][0], 0, 0, 0);
            acc2[0][1] = __builtin_amdgcn_mfma_f32_16x16x32_bf16(aw2[0][ks], bb1, acc2[0][1], 0, 0, 0);
            acc2[1][0] = __builtin_amdgcn_mfma_f32_16x16x32_bf16(aw2[1][ks], bb0, acc2[1][0], 0, 0, 0);
            acc2[1][1] = __builtin_amdgcn_mfma_f32_16x16x32_bf16(aw2[1][ks], bb1, acc2[1][1], 0, 0, 0);
        }

        // ---- epilogue 2: bias + elu -> f32 msg tile (overlaid on featA) ----
        #pragma unroll
        for (int mi = 0; mi < 2; ++mi) {
            int cb = wv*32 + mi*16 + quad*4;
            #pragma unroll
            for (int ni = 0; ni < 2; ++ni) {
                float4 v = { elu_f(acc2[mi][ni][0] + b2v[mi].x), elu_f(acc2[mi][ni][1] + b2v[mi].y),
                             elu_f(acc2[mi][ni][2] + b2v[mi].z), elu_f(acc2[mi][ni][3] + b2v[mi].w) };
                *(float4*)&msgF[(ni*16 + l15)*MST + cb] = v;
            }
        }
        __syncthreads();

        // ---- segmented reduce: thread (ch, half) walks 16 sorted edges, flush per run ----
        {
            int ch = t & 127, half = t >> 7;
            int base = half * 16;
            int prow = srowS[base];
            float run = 0.0f;
            #pragma unroll
            for (int i = 0; i < 16; ++i) {
                int rr = srowS[base + i];
                if (rr != prow) {
                    unsafeAtomicAdd(&agg[(size_t)prow * HID + ch], run);
                    run = 0.0f; prow = rr;
                }
                run += msgF[(base + i)*MST + ch];
            }
            unsafeAtomicAdd(&agg[(size_t)prow * HID + ch], run);
        }
    }
}

// ---------------- MFMA node MLP: register weights, NTN tiles/block, optional agg re-zero ----------------
__global__ __launch_bounds__(256) void node_mfma_kernel(
    const short* __restrict__ h_bf, float* __restrict__ agg,
    const short* __restrict__ w1T, const float* __restrict__ b1,
    const short* __restrict__ w2T, const float* __restrict__ b2,
    short* __restrict__ hout_bf, int zero_agg)
{
    __shared__ short featN[32 * NST];   // 16896 B
    __shared__ short t1[32 * TST];      // 8704 B
    int t = threadIdx.x;
    int lane = t & 63;
    int wv = t >> 6;
    int l15 = lane & 15;
    int quad = lane >> 4;
    int nl = t >> 3, j = t & 7;

    // ---- preload this wave's weight fragments (once) ----
    short8 aw1[2][8], aw2[2][4];
    float4 b1v[2], b2v[2];
    #pragma unroll
    for (int mi = 0; mi < 2; ++mi) {
        #pragma unroll
        for (int ks = 0; ks < 8; ++ks)
            aw1[mi][ks] = *(const short8*)&w1T[(size_t)(wv*32 + mi*16 + l15)*KN + ks*32 + quad*8];
        #pragma unroll
        for (int ks = 0; ks < 4; ++ks)
            aw2[mi][ks] = *(const short8*)&w2T[(size_t)(wv*32 + mi*16 + l15)*128 + ks*32 + quad*8];
        b1v[mi] = *(const float4*)&b1[wv*32 + mi*16 + quad*4];
        b2v[mi] = *(const float4*)&b2[wv*32 + mi*16 + quad*4];
    }

    for (int it = 0; it < NTN; ++it) {
        int n0 = (blockIdx.x * NTN + it) * 32;
        if (n0 >= N_NODES) break;          // block-uniform
        __syncthreads();

        int n = n0 + nl;
        int idx = n < N_NODES ? n : N_NODES - 1;
        {
            const short8* hp = (const short8*)(h_bf + (size_t)idx * HID + j*16);
            short8 s0 = hp[0], s1 = hp[1];
            const float4* ap = (const float4*)(agg + (size_t)idx * HID) + j*4;
            float4 u0 = ap[0], u1 = ap[1], u2 = ap[2], u3 = ap[3];
            short2 p0 = f2bf2(u0.x, u0.y), p1 = f2bf2(u0.z, u0.w);
            short2 p2 = f2bf2(u1.x, u1.y), p3 = f2bf2(u1.z, u1.w);
            short2 p4 = f2bf2(u2.x, u2.y), p5 = f2bf2(u2.z, u2.w);
            short2 p6 = f2bf2(u3.x, u3.y), p7 = f2bf2(u3.z, u3.w);
            short8 s2 = { p0.x, p0.y, p1.x, p1.y, p2.x, p2.y, p3.x, p3.y };
            short8 s3 = { p4.x, p4.y, p5.x, p5.y, p6.x, p6.y, p7.x, p7.y };
            *(short8*)&featN[nl*NST + j*16]       = s0;
            *(short8*)&featN[nl*NST + j*16 + 8]   = s1;
            *(short8*)&featN[nl*NST + 128 + j*16]     = s2;
            *(short8*)&featN[nl*NST + 128 + j*16 + 8] = s3;
        }
        __syncthreads();

        // ---- re-zero consumed agg rows for the next layer (block owns these rows) ----
        if (zero_agg && n < N_NODES) {
            float4 z = {0,0,0,0};
            float4* ap = (float4*)(agg + (size_t)n * HID) + j*4;
            ap[0] = z; ap[1] = z; ap[2] = z; ap[3] = z;
        }

        floatx4 acc[2][2] = {{{0,0,0,0},{0,0,0,0}},{{0,0,0,0},{0,0,0,0}}};
        #pragma unroll
        for (int ks = 0; ks < 8; ++ks) {
            int koff = ks*32 + quad*8;
            short8 bb0 = *(const short8*)&featN[l15*NST + koff];
            short8 bb1 = *(const short8*)&featN[(16 + l15)*NST + koff];
            acc[0][0] = __builtin_amdgcn_mfma_f32_16x16x32_bf16(aw1[0][ks], bb0, acc[0][0], 0, 0, 0);
            acc[0][1] = __builtin_amdgcn_mfma_f32_16x16x32_bf16(aw1[0][ks], bb1, acc[0][1], 0, 0, 0);
            acc[1][0] = __builtin_amdgcn_mfma_f32_16x16x32_bf16(aw1[1][ks], bb0, acc[1][0], 0, 0, 0);
            acc[1][1] = __builtin_amdgcn_mfma_f32_16x16x32_bf16(aw1[1][ks], bb1, acc[1][1], 0, 0, 0);
        }

        #pragma unroll
        for (int mi = 0; mi < 2; ++mi) {
            int cb = wv*32 + mi*16 + quad*4;
            #pragma unroll
            for (int ni = 0; ni < 2; ++ni) {
                short2 p0 = f2bf2(elu_f(acc[mi][ni][0] + b1v[mi].x),
                                  elu_f(acc[mi][ni][1] + b1v[mi].y));
                short2 p1 = f2bf2(elu_f(acc[mi][ni][2] + b1v[mi].z),
                                  elu_f(acc[mi][ni][3] + b1v[mi].w));
                short4v s = { p0.x, p0.y, p1.x, p1.y };
                *(short4v*)&t1[(ni*16 + l15)*TST + cb] = s;
            }
        }
        __syncthreads();

        floatx4 acc2[2][2] = {{{0,0,0,0},{0,0,0,0}},{{0,0,0,0},{0,0,0,0}}};
        #pragma unroll
        for (int ks = 0; ks < 4; ++ks) {
            int koff = ks*32 + quad*8;
            short8 bb0 = *(const short8*)&t1[l15*TST + koff];
            short8 bb1 = *(const short8*)&t1[(16 + l15)*TST + koff];
            acc2[0][0] = __builtin_amdgcn_mfma_f32_16x16x32_bf16(aw2[0][ks], bb0, acc2[0][0], 0, 0, 0);
            acc2[0][1] = __builtin_amdgcn_mfma_f32_16x16x32_bf16(aw2[0][ks], bb1, acc2[0][1], 0, 0, 0);
            acc2[1][0] = __builtin_amdgcn_mfma_f32_16x16x32_bf16(aw2[1][ks], bb0, acc2[1][0], 0, 0, 0);
            acc2[1][1] = __builtin_amdgcn_mfma_f32_16x16x32_bf16(aw2[1][ks], bb1, acc2[1][1], 0, 0, 0);
        }

        #pragma unroll
        for (int mi = 0; mi < 2; ++mi) {
            int cb = wv*32 + mi*16 + quad*4;
            #pragma unroll
            for (int ni = 0; ni < 2; ++ni) {
                int nn = n0 + ni*16 + l15;
                if (nn < N_NODES) {
                    short2 p0 = f2bf2(acc2[mi][ni][0] + b2v[mi].x, acc2[mi][ni][1] + b2v[mi].y);
                    short2 p1 = f2bf2(acc2[mi][ni][2] + b2v[mi].z, acc2[mi][ni][3] + b2v[mi].w);
                    short4v s = { p0.x, p0.y, p1.x, p1.y };
                    *(short4v*)&hout_bf[(size_t)nn*HID + cb] = s;
                }
            }
        }
    }
}

// ---------------- output head: z = mu + 0.01*eps*exp(0.5*logvar), bf16 h ----------------
__global__ void out_kernel(const short* __restrict__ h_bf, const float* __restrict__ label,
                           const float* __restrict__ eps,
                           const float* __restrict__ mu_w, const float* __restrict__ mu_b,
                           const float* __restrict__ var_w, const float* __restrict__ var_b,
                           float* __restrict__ z)
{
    int t = threadIdx.x;
    int n = blockIdx.x * 4 + (t >> 6);
    int c = t & 63;
    if (n >= N_NODES) return;
    float am = mu_b[c], av = var_b[c];
    #pragma unroll 4
    for (int k = 0; k < HID; ++k) {
        float hv = bf2f(h_bf[(size_t)n*HID + k]);
        am += hv * mu_w[k*LAT + c];
        av += hv * var_w[k*LAT + c];
    }
    #pragma unroll
    for (int k = 0; k < 7; ++k) {
        float lv = label[(size_t)n*7 + k];
        am += lv * mu_w[(HID+k)*LAT + c];
        av += lv * var_w[(HID+k)*LAT + c];
    }
    float sd = expf(av * 0.5f);
    z[(size_t)n*LAT + c] = am + 0.01f * eps[(size_t)n*LAT + c] * sd;
}

extern "C" void kernel_launch(void* const* d_in, const int* in_sizes, int n_in,
                              void* d_out, int out_size, void* d_ws, size_t ws_size,
                              hipStream_t stream) {
    const float* h0        = (const float*)d_in[0];
    const float* label     = (const float*)d_in[1];
    const float* x         = (const float*)d_in[2];
    const float* edge_attr = (const float*)d_in[3];
    const float* eps       = (const float*)d_in[4];
    const float* emb_w     = (const float*)d_in[5];
    const float* emb_b     = (const float*)d_in[6];
    const float* edge_w1   = (const float*)d_in[7];
    const float* edge_b1   = (const float*)d_in[8];
    const float* edge_w2   = (const float*)d_in[9];
    const float* edge_b2   = (const float*)d_in[10];
    const float* node_w1   = (const float*)d_in[11];
    const float* node_b1   = (const float*)d_in[12];
    const float* node_w2   = (const float*)d_in[13];
    const float* node_b2   = (const float*)d_in[14];
    const float* mu_w      = (const float*)d_in[15];
    const float* mu_b      = (const float*)d_in[16];
    const float* var_w     = (const float*)d_in[17];
    const float* var_b     = (const float*)d_in[18];
    const int*   edges     = (const int*)d_in[19];
    float* out = (float*)d_out;

    float* agg      = (float*)d_ws;                     // N*128 f32
    short* h_bf     = (short*)(agg + (size_t)N_NODES * HID);  // N*128 bf16
    short* tail_u   = h_bf + (size_t)N_NODES * HID;     // E*8 bf16 (unsorted)
    short* tail_s   = tail_u + (size_t)N_EDGES * 8;     // E*8 bf16 (sorted)
    int*   cnt      = (int*)(tail_s + (size_t)N_EDGES * 8);   // N int
    int*   cursor   = cnt + N_NODES;                    // N int
    int*   blk      = cursor + N_NODES;                 // 256 int
    int*   srow     = blk + 256;                        // E int
    int*   scol     = srow + N_EDGES;                   // E int
    short* ew1T     = (short*)(scol + N_EDGES);         // 2*128*288
    short* ew2T     = ew1T + 2*128*KP1;                 // 2*128*128
    short* nw1T     = ew2T + 2*128*128;                 // 2*128*256
    short* nw2T     = nw1T + 2*128*KN;                  // 2*128*128

    hipMemsetAsync(cnt, 0, N_NODES * sizeof(int), stream);
    prep_all<<<EB + EMB_B + WPB + ZB, 256, 0, stream>>>(
        edges, x, edge_attr, h0, emb_w, emb_b,
        edge_w1, edge_w2, node_w1, node_w2,
        cnt, tail_u, h_bf, ew1T, ew2T, nw1T, nw2T, agg);
    scan_a<<<NSCAN, 256, 0, stream>>>(cnt, cursor, blk);
    scan_b<<<1, 256, 0, stream>>>(blk);
    csr_place<<<(N_EDGES + 255) / 256, 256, 0, stream>>>(edges, tail_u, cursor, blk,
                                                         srow, scol, tail_s);

    for (int l = 0; l < 2; ++l) {
        edge_mfma_kernel<<<N_EDGES / 32 / NTPB, 256, 0, stream>>>(
            h_bf, tail_s, srow, scol,
            ew1T + (size_t)l * 128 * KP1, edge_b1 + l * HID,
            ew2T + (size_t)l * 128 * 128, edge_b2 + l * HID, agg);
        node_mfma_kernel<<<(N_NODES/32 + NTN) / NTN, 256, 0, stream>>>(
            h_bf, agg,
            nw1T + (size_t)l * 128 * KN, node_b1 + l * HID,
            nw2T + (size_t)l * 128 * 128, node_b2 + l * HID, h_bf,
            (l == 0) ? 1 : 0);
    }

    out_kernel<<<N_NODES / 4, 256, 0, stream>>>(h_bf, label, eps, mu_w, mu_b,
                                                var_w, var_b, out);
}

// Round 12
// 741.470 us; speedup vs baseline: 1.0525x; 1.0525x over previous
//
#include <hip/hip_runtime.h>
#include <hip/hip_bf16.h>
#include <math.h>

#define N_NODES 50000
#define N_EDGES 800000
#define HID 128
#define LAT 64
#define IN_NODE 11
#define K_EDGE 261    // 2*HID + 1 + 4
#define KP1 288       // K_EDGE padded to multiple of 32
#define KN 256        // node MLP folded K (h + agg)
#define AST 296       // edge feature LDS row stride (bf16 elems), 288+8 pad
#define NST 264       // node feature LDS row stride, 256+8 pad
#define TST 136       // t1 LDS row stride, 128+8 pad
#define MST 132       // msg LDS row stride (floats), 128+4 pad
#define NTPB 20       // edge tiles per block (grid 1250)
#define NTN 4         // node tiles per block (grid 391)
#define NSCAN 196     // scan blocks: 196*256 = 50176 >= N_NODES
// prep_all block partition
#define EB 3125       // edge count+tail blocks
#define EMB_B 25000   // embedding blocks (2 nodes each)
#define WPB 32        // weight prep blocks
#define ZB 100        // agg zero blocks

typedef __attribute__((ext_vector_type(8))) short short8;
typedef __attribute__((ext_vector_type(4))) short short4v;
typedef __attribute__((ext_vector_type(4))) float floatx4;

__device__ __forceinline__ float elu_f(float v) { return v > 0.0f ? v : __expf(v) - 1.0f; }

__device__ __forceinline__ short f2bf(float f) {
    unsigned int u = __builtin_bit_cast(unsigned int, f);
    u += 0x7fffu + ((u >> 16) & 1u);   // round-to-nearest-even
    return (short)(u >> 16);
}

__device__ __forceinline__ short2 f2bf2(float a, float b) {
    float2 p; p.x = a; p.y = b;
    __hip_bfloat162 h = __float22bfloat162_rn(p);   // v_cvt_pk_bf16_f32
    short2 r;
    __builtin_memcpy(&r, &h, sizeof(r));
    return r;
}

__device__ __forceinline__ float bf2f(short s) {
    unsigned int u = ((unsigned int)(unsigned short)s) << 16;
    return __builtin_bit_cast(float, u);
}

// ---------------- fused prep: edge count+tail | emb | weight prep | agg zero ----------------
__global__ void prep_all(const int* __restrict__ edges, const float* __restrict__ x,
                         const float* __restrict__ edge_attr, const float* __restrict__ h0,
                         const float* __restrict__ emb_w, const float* __restrict__ emb_b,
                         const float* __restrict__ ew1, const float* __restrict__ ew2,
                         const float* __restrict__ nw1, const float* __restrict__ nw2,
                         int* __restrict__ cnt, short* __restrict__ tail_u,
                         short* __restrict__ h_bf,
                         short* __restrict__ ew1T, short* __restrict__ ew2T,
                         short* __restrict__ nw1T, short* __restrict__ nw2T,
                         float* __restrict__ agg) {
    int b = blockIdx.x, t = threadIdx.x;
    if (b < EB) {
        // ---- edge: count + radial + bf16 tail pack ----
        int e = b * 256 + t;
        if (e >= N_EDGES) return;
        int r = edges[e], c = edges[N_EDGES + e];
        atomicAdd(&cnt[r], 1);
        float dx = x[r*3+0] - x[c*3+0];
        float dy = x[r*3+1] - x[c*3+1];
        float dz = x[r*3+2] - x[c*3+2];
        float radial = dx*dx + dy*dy + dz*dz;
        float4 ea = *(const float4*)(edge_attr + (size_t)e * 4);
        short8 s = { f2bf(radial), f2bf(ea.x), f2bf(ea.y), f2bf(ea.z), f2bf(ea.w), 0, 0, 0 };
        *(short8*)(tail_u + (size_t)e * 8) = s;
    } else if (b < EB + EMB_B) {
        // ---- embedding: h_bf = bf16(h0 @ emb_w + emb_b) ----
        int bb = b - EB;
        int n = bb * 2 + (t >> 7);
        int c = t & 127;
        if (n >= N_NODES) return;
        float acc = emb_b[c];
        #pragma unroll
        for (int k = 0; k < IN_NODE; ++k) acc += h0[n*IN_NODE + k] * emb_w[k*HID + c];
        h_bf[(size_t)n*HID + c] = f2bf(acc);
    } else if (b < EB + EMB_B + WPB) {
        // ---- weight prep: transpose + bf16 + pad/fold ----
        int idx = (b - EB - EMB_B) * 256 + t;
        int stride = WPB * 256;
        for (int i = idx; i < 2*128*KP1; i += stride) {
            int l = i / (128*KP1); int r = i % (128*KP1);
            int c = r / KP1; int k = r % KP1;
            float v = (k < K_EDGE) ? ew1[(size_t)l*K_EDGE*128 + (size_t)k*128 + c] : 0.0f;
            ew1T[i] = f2bf(v);
        }
        for (int i = idx; i < 2*128*128; i += stride) {
            int l = i / (128*128); int r = i % (128*128);
            int c = r / 128; int k = r % 128;
            ew2T[i] = f2bf(ew2[(size_t)l*128*128 + (size_t)k*128 + c]);
        }
        for (int i = idx; i < 2*128*KN; i += stride) {
            int l = i / (128*KN); int r = i % (128*KN);
            int c = r / KN; int k = r % KN;
            const float* base = nw1 + (size_t)l*384*128;
            float v = (k < 128) ? (base[(size_t)k*128 + c] + base[(size_t)(256+k)*128 + c])
                                : base[(size_t)k*128 + c];
            nw1T[i] = f2bf(v);
        }
        for (int i = idx; i < 2*128*128; i += stride) {
            int l = i / (128*128); int r = i % (128*128);
            int c = r / 128; int k = r % 128;
            nw2T[i] = f2bf(nw2[(size_t)l*128*128 + (size_t)k*128 + c]);
        }
    } else {
        // ---- agg zero ----
        int idx = (b - EB - EMB_B - WPB) * 256 + t;
        int stride = ZB * 256;
        float4 z = {0,0,0,0};
        float4* a4 = (float4*)agg;
        for (int i = idx; i < N_NODES*HID/4; i += stride) a4[i] = z;
    }
}

// ---------------- CSR pass 2a: per-block exclusive scan (256 rows/block) ----------------
__global__ void scan_a(const int* __restrict__ cnt, int* __restrict__ cursor,
                       int* __restrict__ blk) {
    __shared__ int s[256];
    int b = blockIdx.x, t = threadIdx.x;
    int row = b * 256 + t;
    int v = (row < N_NODES) ? cnt[row] : 0;
    s[t] = v;
    __syncthreads();
    #pragma unroll
    for (int off = 1; off < 256; off <<= 1) {
        int add = (t >= off) ? s[t - off] : 0;
        __syncthreads();
        s[t] += add;
        __syncthreads();
    }
    if (row < N_NODES) cursor[row] = s[t] - v;     // exclusive within block
    if (t == 255) blk[b] = s[255];                 // block total
}

// ---------------- CSR pass 2b: exclusivize the 196 block totals ----------------
__global__ void scan_b(int* __restrict__ blk) {
    __shared__ int s[256];
    int t = threadIdx.x;
    int v = (t < NSCAN) ? blk[t] : 0;
    s[t] = v;
    __syncthreads();
    #pragma unroll
    for (int off = 1; off < 256; off <<= 1) {
        int add = (t >= off) ? s[t - off] : 0;
        __syncthreads();
        s[t] += add;
        __syncthreads();
    }
    if (t < NSCAN) blk[t] = s[t] - v;              // exclusive block offset
}

// ---------------- CSR pass 3: place srow/scol/tail in sorted order ----------------
__global__ void csr_place(const int* __restrict__ edges, const short* __restrict__ tail_u,
                          int* __restrict__ cursor, const int* __restrict__ blk,
                          int* __restrict__ srow, int* __restrict__ scol,
                          short* __restrict__ tail_s) {
    int e = blockIdx.x * 256 + threadIdx.x;
    if (e >= N_EDGES) return;
    int r = edges[e], c = edges[N_EDGES + e];
    short8 s = *(const short8*)(tail_u + (size_t)e * 8);
    int pos = atomicAdd(&cursor[r], 1) + blk[r >> 8];
    srow[pos] = r; scol[pos] = c;
    *(short8*)(tail_s + (size_t)pos * 8) = s;
}

// ---------------- MFMA edge MLP: register weights, NTPB tiles/block, msg overlaid ----------------
__global__ __launch_bounds__(256, 2) void edge_mfma_kernel(
    const short* __restrict__ h_bf, const short* __restrict__ tail_s,
    const int* __restrict__ srow, const int* __restrict__ scol,
    const short* __restrict__ w1T, const float* __restrict__ b1,
    const short* __restrict__ w2T, const float* __restrict__ b2,
    float* __restrict__ agg)
{
    __shared__ __align__(16) short featA[32 * AST];   // 18944 B; msg overlays here
    __shared__ __align__(16) short t1[32 * TST];      // 8704 B
    __shared__ int srowS[32];
    float* msgF = (float*)featA;                      // 32 x MST floats = 16896 B <= featA
    int t = threadIdx.x;
    int lane = t & 63;
    int wv = t >> 6;          // wave: channel block [wv*32, wv*32+32)
    int l15 = lane & 15;
    int quad = lane >> 4;
    int el = t >> 3, j = t & 7;

    // ---- preload this wave's weight fragments into registers (once) ----
    short8 aw1[2][9], aw2[2][4];
    float4 b1v[2], b2v[2];
    #pragma unroll
    for (int mi = 0; mi < 2; ++mi) {
        #pragma unroll
        for (int ks = 0; ks < 9; ++ks)
            aw1[mi][ks] = *(const short8*)&w1T[(size_t)(wv*32 + mi*16 + l15)*KP1 + ks*32 + quad*8];
        #pragma unroll
        for (int ks = 0; ks < 4; ++ks)
            aw2[mi][ks] = *(const short8*)&w2T[(size_t)(wv*32 + mi*16 + l15)*128 + ks*32 + quad*8];
        b1v[mi] = *(const float4*)&b1[wv*32 + mi*16 + quad*4];
        b2v[mi] = *(const float4*)&b2[wv*32 + mi*16 + quad*4];
    }

    for (int it = 0; it < NTPB; ++it) {
        int e0 = (blockIdx.x * NTPB + it) * 32;
        __syncthreads();   // prior iteration's msg reads done before featA overwrite

        // ---- stage 32 edges' gathered bf16 features ----
        {
            int e = e0 + el;
            int r = srow[e], c = scol[e];
            if (j == 0) srowS[el] = r;
            const short8* hr = (const short8*)(h_bf + (size_t)r * HID + j*16);
            const short8* hc = (const short8*)(h_bf + (size_t)c * HID + j*16);
            short8 s0 = hr[0], s1 = hr[1];
            short8 s2 = hc[0], s3 = hc[1];
            *(short8*)&featA[el*AST + j*16]       = s0;
            *(short8*)&featA[el*AST + j*16 + 8]   = s1;
            *(short8*)&featA[el*AST + 128 + j*16]     = s2;
            *(short8*)&featA[el*AST + 128 + j*16 + 8] = s3;
        }
        if (t < 32) {
            int e = e0 + t;
            short8 s = *(const short8*)(tail_s + (size_t)e * 8);
            short8 z = {0,0,0,0,0,0,0,0};
            *(short8*)&featA[t*AST + 256] = s;
            *(short8*)&featA[t*AST + 264] = z;
            *(short8*)&featA[t*AST + 272] = z;
            *(short8*)&featA[t*AST + 280] = z;
        }
        __syncthreads();

        // ---- layer 1: K = 288, A resident ----
        floatx4 acc[2][2] = {{{0,0,0,0},{0,0,0,0}},{{0,0,0,0},{0,0,0,0}}};
        #pragma unroll
        for (int ks = 0; ks < 9; ++ks) {
            int koff = ks*32 + quad*8;
            short8 bb0 = *(const short8*)&featA[l15*AST + koff];
            short8 bb1 = *(const short8*)&featA[(16 + l15)*AST + koff];
            acc[0][0] = __builtin_amdgcn_mfma_f32_16x16x32_bf16(aw1[0][ks], bb0, acc[0][0], 0, 0, 0);
            acc[0][1] = __builtin_amdgcn_mfma_f32_16x16x32_bf16(aw1[0][ks], bb1, acc[0][1], 0, 0, 0);
            acc[1][0] = __builtin_amdgcn_mfma_f32_16x16x32_bf16(aw1[1][ks], bb0, acc[1][0], 0, 0, 0);
            acc[1][1] = __builtin_amdgcn_mfma_f32_16x16x32_bf16(aw1[1][ks], bb1, acc[1][1], 0, 0, 0);
        }

        // ---- epilogue 1: bias + elu -> bf16 t1[e][c] (packed cvt) ----
        #pragma unroll
        for (int mi = 0; mi < 2; ++mi) {
            int cb = wv*32 + mi*16 + quad*4;
            #pragma unroll
            for (int ni = 0; ni < 2; ++ni) {
                short2 q0 = f2bf2(elu_f(acc[mi][ni][0] + b1v[mi].x),
                                  elu_f(acc[mi][ni][1] + b1v[mi].y));
                short2 q1 = f2bf2(elu_f(acc[mi][ni][2] + b1v[mi].z),
                                  elu_f(acc[mi][ni][3] + b1v[mi].w));
                short4v s = { q0.x, q0.y, q1.x, q1.y };
                *(short4v*)&t1[(ni*16 + l15)*TST + cb] = s;
            }
        }
        __syncthreads();   // featA reads done (L1 K-loop) -> msg overlay safe after here

        // ---- layer 2: K = 128, A resident ----
        floatx4 acc2[2][2] = {{{0,0,0,0},{0,0,0,0}},{{0,0,0,0},{0,0,0,0}}};
        #pragma unroll
        for (int ks = 0; ks < 4; ++ks) {
            int koff = ks*32 + quad*8;
            short8 bb0 = *(const short8*)&t1[l15*TST + koff];
            short8 bb1 = *(const short8*)&t1[(16 + l15)*TST + koff];
            acc2[0][0] = __builtin_amdgcn_mfma_f32_16x16x32_bf16(aw2[0][ks], bb0, acc2[0][0], 0, 0, 0);
            acc2[0][1] = __builtin_amdgcn_mfma_f32_16x16x32_bf16(aw2[0][ks], bb1, acc2[0][1], 0, 0, 0);
            acc2[1][0] = __builtin_amdgcn_mfma_f32_16x16x32_bf16(aw2[1][ks], bb0, acc2[1][0], 0, 0, 0);
            acc2[1][1] = __builtin_amdgcn_mfma_f32_16x16x32_bf16(aw2[1][ks], bb1, acc2[1][1], 0, 0, 0);
        }

        // ---- epilogue 2: bias + elu -> f32 msg tile (overlaid on featA) ----
        #pragma unroll
        for (int mi = 0; mi < 2; ++mi) {
            int cb = wv*32 + mi*16 + quad*4;
            #pragma unroll
            for (int ni = 0; ni < 2; ++ni) {
                float4 v = { elu_f(acc2[mi][ni][0] + b2v[mi].x), elu_f(acc2[mi][ni][1] + b2v[mi].y),
                             elu_f(acc2[mi][ni][2] + b2v[mi].z), elu_f(acc2[mi][ni][3] + b2v[mi].w) };
                *(float4*)&msgF[(ni*16 + l15)*MST + cb] = v;
            }
        }
        __syncthreads();

        // ---- segmented reduce: thread (ch, half) walks 16 sorted edges, flush per run ----
        {
            int ch = t & 127, half = t >> 7;
            int base = half * 16;
            int prow = srowS[base];
            float run = 0.0f;
            #pragma unroll
            for (int i = 0; i < 16; ++i) {
                int rr = srowS[base + i];
                if (rr != prow) {
                    unsafeAtomicAdd(&agg[(size_t)prow * HID + ch], run);
                    run = 0.0f; prow = rr;
                }
                run += msgF[(base + i)*MST + ch];
            }
            unsafeAtomicAdd(&agg[(size_t)prow * HID + ch], run);
        }
    }
}

// ---------------- MFMA node MLP: register weights, NTN tiles/block, optional agg re-zero ----------------
__global__ __launch_bounds__(256) void node_mfma_kernel(
    const short* __restrict__ h_bf, float* __restrict__ agg,
    const short* __restrict__ w1T, const float* __restrict__ b1,
    const short* __restrict__ w2T, const float* __restrict__ b2,
    short* __restrict__ hout_bf, int zero_agg)
{
    __shared__ short featN[32 * NST];   // 16896 B
    __shared__ short t1[32 * TST];      // 8704 B
    int t = threadIdx.x;
    int lane = t & 63;
    int wv = t >> 6;
    int l15 = lane & 15;
    int quad = lane >> 4;
    int nl = t >> 3, j = t & 7;

    // ---- preload this wave's weight fragments (once) ----
    short8 aw1[2][8], aw2[2][4];
    float4 b1v[2], b2v[2];
    #pragma unroll
    for (int mi = 0; mi < 2; ++mi) {
        #pragma unroll
        for (int ks = 0; ks < 8; ++ks)
            aw1[mi][ks] = *(const short8*)&w1T[(size_t)(wv*32 + mi*16 + l15)*KN + ks*32 + quad*8];
        #pragma unroll
        for (int ks = 0; ks < 4; ++ks)
            aw2[mi][ks] = *(const short8*)&w2T[(size_t)(wv*32 + mi*16 + l15)*128 + ks*32 + quad*8];
        b1v[mi] = *(const float4*)&b1[wv*32 + mi*16 + quad*4];
        b2v[mi] = *(const float4*)&b2[wv*32 + mi*16 + quad*4];
    }

    for (int it = 0; it < NTN; ++it) {
        int n0 = (blockIdx.x * NTN + it) * 32;
        if (n0 >= N_NODES) break;          // block-uniform
        __syncthreads();

        int n = n0 + nl;
        int idx = n < N_NODES ? n : N_NODES - 1;
        {
            const short8* hp = (const short8*)(h_bf + (size_t)idx * HID + j*16);
            short8 s0 = hp[0], s1 = hp[1];
            const float4* ap = (const float4*)(agg + (size_t)idx * HID) + j*4;
            float4 u0 = ap[0], u1 = ap[1], u2 = ap[2], u3 = ap[3];
            short2 p0 = f2bf2(u0.x, u0.y), p1 = f2bf2(u0.z, u0.w);
            short2 p2 = f2bf2(u1.x, u1.y), p3 = f2bf2(u1.z, u1.w);
            short2 p4 = f2bf2(u2.x, u2.y), p5 = f2bf2(u2.z, u2.w);
            short2 p6 = f2bf2(u3.x, u3.y), p7 = f2bf2(u3.z, u3.w);
            short8 s2 = { p0.x, p0.y, p1.x, p1.y, p2.x, p2.y, p3.x, p3.y };
            short8 s3 = { p4.x, p4.y, p5.x, p5.y, p6.x, p6.y, p7.x, p7.y };
            *(short8*)&featN[nl*NST + j*16]       = s0;
            *(short8*)&featN[nl*NST + j*16 + 8]   = s1;
            *(short8*)&featN[nl*NST + 128 + j*16]     = s2;
            *(short8*)&featN[nl*NST + 128 + j*16 + 8] = s3;
        }
        __syncthreads();

        // ---- re-zero consumed agg rows for the next layer (block owns these rows) ----
        if (zero_agg && n < N_NODES) {
            float4 z = {0,0,0,0};
            float4* ap = (float4*)(agg + (size_t)n * HID) + j*4;
            ap[0] = z; ap[1] = z; ap[2] = z; ap[3] = z;
        }

        floatx4 acc[2][2] = {{{0,0,0,0},{0,0,0,0}},{{0,0,0,0},{0,0,0,0}}};
        #pragma unroll
        for (int ks = 0; ks < 8; ++ks) {
            int koff = ks*32 + quad*8;
            short8 bb0 = *(const short8*)&featN[l15*NST + koff];
            short8 bb1 = *(const short8*)&featN[(16 + l15)*NST + koff];
            acc[0][0] = __builtin_amdgcn_mfma_f32_16x16x32_bf16(aw1[0][ks], bb0, acc[0][0], 0, 0, 0);
            acc[0][1] = __builtin_amdgcn_mfma_f32_16x16x32_bf16(aw1[0][ks], bb1, acc[0][1], 0, 0, 0);
            acc[1][0] = __builtin_amdgcn_mfma_f32_16x16x32_bf16(aw1[1][ks], bb0, acc[1][0], 0, 0, 0);
            acc[1][1] = __builtin_amdgcn_mfma_f32_16x16x32_bf16(aw1[1][ks], bb1, acc[1][1], 0, 0, 0);
        }

        #pragma unroll
        for (int mi = 0; mi < 2; ++mi) {
            int cb = wv*32 + mi*16 + quad*4;
            #pragma unroll
            for (int ni = 0; ni < 2; ++ni) {
                short2 p0 = f2bf2(elu_f(acc[mi][ni][0] + b1v[mi].x),
                                  elu_f(acc[mi][ni][1] + b1v[mi].y));
                short2 p1 = f2bf2(elu_f(acc[mi][ni][2] + b1v[mi].z),
                                  elu_f(acc[mi][ni][3] + b1v[mi].w));
                short4v s = { p0.x, p0.y, p1.x, p1.y };
                *(short4v*)&t1[(ni*16 + l15)*TST + cb] = s;
            }
        }
        __syncthreads();

        floatx4 acc2[2][2] = {{{0,0,0,0},{0,0,0,0}},{{0,0,0,0},{0,0,0,0}}};
        #pragma unroll
        for (int ks = 0; ks < 4; ++ks) {
            int koff = ks*32 + quad*8;
            short8 bb0 = *(const short8*)&t1[l15*TST + koff];
            short8 bb1 = *(const short8*)&t1[(16 + l15)*TST + koff];
            acc2[0][0] = __builtin_amdgcn_mfma_f32_16x16x32_bf16(aw2[0][ks], bb0, acc2[0][0], 0, 0, 0);
            acc2[0][1] = __builtin_amdgcn_mfma_f32_16x16x32_bf16(aw2[0][ks], bb1, acc2[0][1], 0, 0, 0);
            acc2[1][0] = __builtin_amdgcn_mfma_f32_16x16x32_bf16(aw2[1][ks], bb0, acc2[1][0], 0, 0, 0);
            acc2[1][1] = __builtin_amdgcn_mfma_f32_16x16x32_bf16(aw2[1][ks], bb1, acc2[1][1], 0, 0, 0);
        }

        #pragma unroll
        for (int mi = 0; mi < 2; ++mi) {
            int cb = wv*32 + mi*16 + quad*4;
            #pragma unroll
            for (int ni = 0; ni < 2; ++ni) {
                int nn = n0 + ni*16 + l15;
                if (nn < N_NODES) {
                    short2 p0 = f2bf2(acc2[mi][ni][0] + b2v[mi].x, acc2[mi][ni][1] + b2v[mi].y);
                    short2 p1 = f2bf2(acc2[mi][ni][2] + b2v[mi].z, acc2[mi][ni][3] + b2v[mi].w);
                    short4v s = { p0.x, p0.y, p1.x, p1.y };
                    *(short4v*)&hout_bf[(size_t)nn*HID + cb] = s;
                }
            }
        }
    }
}

// ---------------- output head: z = mu + 0.01*eps*exp(0.5*logvar), bf16 h ----------------
__global__ void out_kernel(const short* __restrict__ h_bf, const float* __restrict__ label,
                           const float* __restrict__ eps,
                           const float* __restrict__ mu_w, const float* __restrict__ mu_b,
                           const float* __restrict__ var_w, const float* __restrict__ var_b,
                           float* __restrict__ z)
{
    int t = threadIdx.x;
    int n = blockIdx.x * 4 + (t >> 6);
    int c = t & 63;
    if (n >= N_NODES) return;
    float am = mu_b[c], av = var_b[c];
    #pragma unroll 4
    for (int k = 0; k < HID; ++k) {
        float hv = bf2f(h_bf[(size_t)n*HID + k]);
        am += hv * mu_w[k*LAT + c];
        av += hv * var_w[k*LAT + c];
    }
    #pragma unroll
    for (int k = 0; k < 7; ++k) {
        float lv = label[(size_t)n*7 + k];
        am += lv * mu_w[(HID+k)*LAT + c];
        av += lv * var_w[(HID+k)*LAT + c];
    }
    float sd = expf(av * 0.5f);
    z[(size_t)n*LAT + c] = am + 0.01f * eps[(size_t)n*LAT + c] * sd;
}

extern "C" void kernel_launch(void* const* d_in, const int* in_sizes, int n_in,
                              void* d_out, int out_size, void* d_ws, size_t ws_size,
                              hipStream_t stream) {
    const float* h0        = (const float*)d_in[0];
    const float* label     = (const float*)d_in[1];
    const float* x         = (const float*)d_in[2];
    const float* edge_attr = (const float*)d_in[3];
    const float* eps       = (const float*)d_in[4];
    const float* emb_w     = (const float*)d_in[5];
    const float* emb_b     = (const float*)d_in[6];
    const float* edge_w1   = (const float*)d_in[7];
    const float* edge_b1   = (const float*)d_in[8];
    const float* edge_w2   = (const float*)d_in[9];
    const float* edge_b2   = (const float*)d_in[10];
    const float* node_w1   = (const float*)d_in[11];
    const float* node_b1   = (const float*)d_in[12];
    const float* node_w2   = (const float*)d_in[13];
    const float* node_b2   = (const float*)d_in[14];
    const float* mu_w      = (const float*)d_in[15];
    const float* mu_b      = (const float*)d_in[16];
    const float* var_w     = (const float*)d_in[17];
    const float* var_b     = (const float*)d_in[18];
    const int*   edges     = (const int*)d_in[19];
    float* out = (float*)d_out;

    float* agg      = (float*)d_ws;                     // N*128 f32
    short* h_bf     = (short*)(agg + (size_t)N_NODES * HID);  // N*128 bf16
    short* tail_u   = h_bf + (size_t)N_NODES * HID;     // E*8 bf16 (unsorted)
    short* tail_s   = tail_u + (size_t)N_EDGES * 8;     // E*8 bf16 (sorted)
    int*   cnt      = (int*)(tail_s + (size_t)N_EDGES * 8);   // N int
    int*   cursor   = cnt + N_NODES;                    // N int
    int*   blk      = cursor + N_NODES;                 // 256 int
    int*   srow     = blk + 256;                        // E int
    int*   scol     = srow + N_EDGES;                   // E int
    short* ew1T     = (short*)(scol + N_EDGES);         // 2*128*288
    short* ew2T     = ew1T + 2*128*KP1;                 // 2*128*128
    short* nw1T     = ew2T + 2*128*128;                 // 2*128*256
    short* nw2T     = nw1T + 2*128*KN;                  // 2*128*128

    hipMemsetAsync(cnt, 0, N_NODES * sizeof(int), stream);
    prep_all<<<EB + EMB_B + WPB + ZB, 256, 0, stream>>>(
        edges, x, edge_attr, h0, emb_w, emb_b,
        edge_w1, edge_w2, node_w1, node_w2,
        cnt, tail_u, h_bf, ew1T, ew2T, nw1T, nw2T, agg);
    scan_a<<<NSCAN, 256, 0, stream>>>(cnt, cursor, blk);
    scan_b<<<1, 256, 0, stream>>>(blk);
    csr_place<<<(N_EDGES + 255) / 256, 256, 0, stream>>>(edges, tail_u, cursor, blk,
                                                         srow, scol, tail_s);

    for (int l = 0; l < 2; ++l) {
        edge_mfma_kernel<<<N_EDGES / 32 / NTPB, 256, 0, stream>>>(
            h_bf, tail_s, srow, scol,
            ew1T + (size_t)l * 128 * KP1, edge_b1 + l * HID,
            ew2T + (size_t)l * 128 * 128, edge_b2 + l * HID, agg);
        node_mfma_kernel<<<(N_NODES/32 + NTN) / NTN, 256, 0, stream>>>(
            h_bf, agg,
            nw1T + (size_t)l * 128 * KN, node_b1 + l * HID,
            nw2T + (size_t)l * 128 * 128, node_b2 + l * HID, h_bf,
            (l == 0) ? 1 : 0);
    }

    out_kernel<<<N_NODES / 4, 256, 0, stream>>>(h_bf, label, eps, mu_w, mu_b,
                                                var_w, var_b, out);
}